// Round 1
// baseline (16368.329 us; speedup 1.0000x reference)
//
#include <hip/hip_runtime.h>

// Problem constants (match the reference file)
constexpr int N = 100000;
constexpr int D = 128;
constexpr int E = 3200000;
constexpr int ND4 = N * (D / 4);   // float4 elements of a [N,D] tensor

// ---------------- degree / normalization ----------------

__global__ void k_deg_init(float* __restrict__ deg) {
    int i = blockIdx.x * blockDim.x + threadIdx.x;
    if (i < N) deg[i] = 1.0f;  // self-loop contributes 1 to every node
}

__global__ void k_deg_count(const int* __restrict__ col, float* __restrict__ deg) {
    int e = blockIdx.x * blockDim.x + threadIdx.x;
    if (e < E) unsafeAtomicAdd(&deg[col[e]], 1.0f);  // HW global_atomic_add_f32
}

__global__ void k_rsqrt(float* __restrict__ deg) {
    int i = blockIdx.x * blockDim.x + threadIdx.x;
    if (i < N) deg[i] = rsqrtf(deg[i]);  // deg >= 1 always (self-loops) -> no inf
}

// ---------------- per-layer kernels ----------------

// h_next[i] = dinv[i]^2 * h[i]   (self-loop message; also serves as the zero-init)
__global__ void k_self_init(const float* __restrict__ h, const float* __restrict__ dinv,
                            float* __restrict__ out) {
    int idx = blockIdx.x * blockDim.x + threadIdx.x;
    if (idx >= ND4) return;
    int i = idx / (D / 4);
    float s = dinv[i] * dinv[i];
    float4 v = reinterpret_cast<const float4*>(h)[idx];
    v.x *= s; v.y *= s; v.z *= s; v.w *= s;
    reinterpret_cast<float4*>(out)[idx] = v;
}

// acc[i] += dinv[i]^2 * h[i]    (last layer's self-loop folded into the accumulator)
__global__ void k_self_add(const float* __restrict__ h, const float* __restrict__ dinv,
                           float* __restrict__ acc) {
    int idx = blockIdx.x * blockDim.x + threadIdx.x;
    if (idx >= ND4) return;
    int i = idx / (D / 4);
    float s = dinv[i] * dinv[i];
    float4 v = reinterpret_cast<const float4*>(h)[idx];
    float4 a = reinterpret_cast<const float4*>(acc)[idx];
    a.x += s * v.x; a.y += s * v.y; a.z += s * v.z; a.w += s * v.w;
    reinterpret_cast<float4*>(acc)[idx] = a;
}

// out[col[e]] += dinv[row]*dinv[col] * h[row]; one thread per (edge, 4-float chunk)
__global__ void k_scatter(const int* __restrict__ row, const int* __restrict__ col,
                          const float* __restrict__ dinv,
                          const float* __restrict__ h, float* __restrict__ out) {
    long long t = (long long)blockIdx.x * blockDim.x + threadIdx.x;
    int e = (int)(t >> 5);           // 32 chunks of float4 cover D=128
    if (e >= E) return;
    int d4 = (int)(t & 31);
    int r = row[e];
    int c = col[e];
    float nrm = dinv[r] * dinv[c];
    float4 v = reinterpret_cast<const float4*>(h + (size_t)r * D)[d4];
    float* o = out + (size_t)c * D + (size_t)d4 * 4;
    unsafeAtomicAdd(o + 0, nrm * v.x);
    unsafeAtomicAdd(o + 1, nrm * v.y);
    unsafeAtomicAdd(o + 2, nrm * v.z);
    unsafeAtomicAdd(o + 3, nrm * v.w);
}

// ---------------- accumulator ----------------

__global__ void k_copy(const float* __restrict__ x, float* __restrict__ acc) {
    int idx = blockIdx.x * blockDim.x + threadIdx.x;
    if (idx >= ND4) return;
    reinterpret_cast<float4*>(acc)[idx] = reinterpret_cast<const float4*>(x)[idx];
}

__global__ void k_add(const float* __restrict__ h, float* __restrict__ acc) {
    int idx = blockIdx.x * blockDim.x + threadIdx.x;
    if (idx >= ND4) return;
    float4 v = reinterpret_cast<const float4*>(h)[idx];
    float4 a = reinterpret_cast<const float4*>(acc)[idx];
    a.x += v.x; a.y += v.y; a.z += v.z; a.w += v.w;
    reinterpret_cast<float4*>(acc)[idx] = a;
}

__global__ void k_scale(float* __restrict__ acc) {
    int idx = blockIdx.x * blockDim.x + threadIdx.x;
    if (idx >= ND4) return;
    float4 a = reinterpret_cast<const float4*>(acc)[idx];
    a.x *= 0.25f; a.y *= 0.25f; a.z *= 0.25f; a.w *= 0.25f;
    reinterpret_cast<float4*>(acc)[idx] = a;
}

extern "C" void kernel_launch(void* const* d_in, const int* in_sizes, int n_in,
                              void* d_out, int out_size, void* d_ws, size_t ws_size,
                              hipStream_t stream) {
    const float* x  = (const float*)d_in[0];
    const int*   ei = (const int*)d_in[1];   // [2, E] row-major: row = ei[0:E], col = ei[E:2E]
    const int*   row = ei;
    const int*   col = ei + E;
    float* out = (float*)d_out;

    // workspace layout: dinv (N floats, 512B aligned) | h1 (N*D) | h2 (N*D)
    char* ws = (char*)d_ws;
    float* dinv = (float*)ws;
    size_t off = ((size_t)N * sizeof(float) + 511) & ~(size_t)511;
    float* h1 = (float*)(ws + off);
    float* h2 = h1 + (size_t)N * D;

    const int B = 256;
    const int gN   = (N + B - 1) / B;
    const int gE1  = (E + B - 1) / B;
    const int gND4 = (ND4 + B - 1) / B;
    const long long tE = (long long)E * 32;
    const int gE32 = (int)((tE + B - 1) / B);

    // normalization
    k_deg_init<<<gN, B, 0, stream>>>(dinv);
    k_deg_count<<<gE1, B, 0, stream>>>(col, dinv);
    k_rsqrt<<<gN, B, 0, stream>>>(dinv);

    // acc = x
    k_copy<<<gND4, B, 0, stream>>>(x, out);

    // layer 1: h1 = conv(x); acc += h1
    k_self_init<<<gND4, B, 0, stream>>>(x, dinv, h1);
    k_scatter<<<gE32, B, 0, stream>>>(row, col, dinv, x, h1);
    k_add<<<gND4, B, 0, stream>>>(h1, out);

    // layer 2: h2 = conv(h1); acc += h2
    k_self_init<<<gND4, B, 0, stream>>>(h1, dinv, h2);
    k_scatter<<<gE32, B, 0, stream>>>(row, col, dinv, h1, h2);
    k_add<<<gND4, B, 0, stream>>>(h2, out);

    // layer 3: scatter conv(h2) straight into acc (addition distributes)
    k_self_add<<<gND4, B, 0, stream>>>(h2, dinv, out);
    k_scatter<<<gE32, B, 0, stream>>>(row, col, dinv, h2, out);

    // acc /= 4
    k_scale<<<gND4, B, 0, stream>>>(out);
}

// Round 2
// 1396.182 us; speedup vs baseline: 11.7236x; 11.7236x over previous
//
#include <hip/hip_runtime.h>

// Problem constants (match the reference file)
constexpr int N = 100000;
constexpr int D = 128;
constexpr int E = 3200000;
constexpr int ND4 = N * (D / 4);   // float4 elements of a [N,D] tensor

// ---------------- CSR build ----------------

__global__ void k_zero(int* __restrict__ p, int n) {
    int i = blockIdx.x * blockDim.x + threadIdx.x;
    if (i < n) p[i] = 0;
}

// cnt[c] = number of edges with col==c (self-loops excluded; handled analytically)
__global__ void k_hist(const int* __restrict__ col, int* __restrict__ cnt) {
    int e = blockIdx.x * blockDim.x + threadIdx.x;
    if (e < E) atomicAdd(&cnt[col[e]], 1);
}

// dinv[i] = rsqrt(cnt[i] + 1)   (+1 = self loop; always >= 1, no inf)
__global__ void k_dinv(const int* __restrict__ cnt, float* __restrict__ dinv) {
    int i = blockIdx.x * blockDim.x + threadIdx.x;
    if (i < N) dinv[i] = rsqrtf((float)(cnt[i] + 1));
}

// single-block exclusive scan: ptr[c] = sum_{j<c} cnt[j]
__global__ void k_scan(const int* __restrict__ cnt, int* __restrict__ ptr) {
    __shared__ int lds[1024];
    __shared__ int carry_s;
    int tid = threadIdx.x;
    if (tid == 0) carry_s = 0;
    __syncthreads();
    for (int base = 0; base < N; base += 1024) {
        int i = base + tid;
        int v = (i < N) ? cnt[i] : 0;
        lds[tid] = v;
        __syncthreads();
        for (int ofs = 1; ofs < 1024; ofs <<= 1) {
            int t = (tid >= ofs) ? lds[tid - ofs] : 0;
            __syncthreads();
            lds[tid] += t;
            __syncthreads();
        }
        int incl = lds[tid];
        int excl = incl - v;
        int carry = carry_s;
        if (i < N) ptr[i] = carry + excl;
        __syncthreads();
        if (tid == 1023) carry_s = carry + incl;   // incl of tid 1023 == chunk total
        __syncthreads();
    }
}

// fill CSR; uses ptr as the cursor. Afterwards ptr[c] == inclusive end of segment c,
// so segment c spans [ptr[c-1], ptr[c]) with ptr[-1] := 0.
__global__ void k_fill(const int* __restrict__ row, const int* __restrict__ col,
                       int* __restrict__ ptr, int* __restrict__ csr_src) {
    int e = blockIdx.x * blockDim.x + threadIdx.x;
    if (e < E) {
        int slot = atomicAdd(&ptr[col[e]], 1);
        csr_src[slot] = row[e];
    }
}

// ---------------- fused gather conv ----------------
// One wave (64 lanes) per destination node; lane owns float2 (D=128 = 64*2).
// r[c] = dinv[c] * ( dinv[c]*h[c] + sum_{e: col==c} dinv[src]*h[src] )
// MODE 1: h_out = r; acc = aux + r        (layer 1, aux = x)
// MODE 2: h_out = r; acc += r             (layer 2)
// MODE 3: acc = (acc + r) * 0.25          (layer 3 + final scale)
template <int MODE>
__global__ void k_gather(const int* __restrict__ ptr, const int* __restrict__ csr_src,
                         const float* __restrict__ dinv,
                         const float* __restrict__ h_in,
                         const float* __restrict__ aux,
                         float* __restrict__ h_out,
                         float* acc) {
    int node = blockIdx.x * (blockDim.x >> 6) + (threadIdx.x >> 6);
    if (node >= N) return;
    node = __builtin_amdgcn_readfirstlane(node);   // wave-uniform -> SGPRs
    int lane = threadIdx.x & 63;

    int beg = (node == 0) ? 0 : ptr[node - 1];
    int end = ptr[node];
    float dc = dinv[node];

    float2 s = reinterpret_cast<const float2*>(h_in + (size_t)node * D)[lane];
    float ax = dc * s.x, ay = dc * s.y;

    for (int t = beg; t < end; ++t) {
        int src = csr_src[t];
        float w = dinv[src];
        float2 v = reinterpret_cast<const float2*>(h_in + (size_t)src * D)[lane];
        ax += w * v.x;
        ay += w * v.y;
    }
    ax *= dc;
    ay *= dc;

    size_t o2 = (size_t)node * (D / 2) + lane;     // float2 index
    if (MODE == 1) {
        float2 xv = reinterpret_cast<const float2*>(aux)[o2];
        reinterpret_cast<float2*>(h_out)[o2] = make_float2(ax, ay);
        reinterpret_cast<float2*>(acc)[o2]   = make_float2(xv.x + ax, xv.y + ay);
    } else if (MODE == 2) {
        float2 av = reinterpret_cast<const float2*>(acc)[o2];
        reinterpret_cast<float2*>(h_out)[o2] = make_float2(ax, ay);
        reinterpret_cast<float2*>(acc)[o2]   = make_float2(av.x + ax, av.y + ay);
    } else {
        float2 av = reinterpret_cast<const float2*>(acc)[o2];
        reinterpret_cast<float2*>(acc)[o2] =
            make_float2((av.x + ax) * 0.25f, (av.y + ay) * 0.25f);
    }
}

extern "C" void kernel_launch(void* const* d_in, const int* in_sizes, int n_in,
                              void* d_out, int out_size, void* d_ws, size_t ws_size,
                              hipStream_t stream) {
    const float* x  = (const float*)d_in[0];
    const int*   ei = (const int*)d_in[1];   // [2, E]: row = ei[0:E], col = ei[E:2E]
    const int*   row = ei;
    const int*   col = ei + E;
    float* out = (float*)d_out;

    // ws layout: cnt[N] | ptr[N] | dinv[N] | csr_src[E] | h1[N*D] | h2[N*D]
    char* ws = (char*)d_ws;
    int*   cnt     = (int*)ws;
    int*   ptr     = cnt + N;
    float* dinv    = (float*)(ptr + N);
    int*   csr_src = (int*)(dinv + N);
    float* h1      = (float*)(csr_src + E);
    float* h2      = h1 + (size_t)N * D;

    const int B = 256;
    const int gN  = (N + B - 1) / B;
    const int gE  = (E + B - 1) / B;
    const int gG  = (N + 3) / 4;             // 4 waves/block, 1 node/wave

    // ---- CSR build + normalization ----
    k_zero<<<gN, B, 0, stream>>>(cnt, N);
    k_hist<<<gE, B, 0, stream>>>(col, cnt);
    k_dinv<<<gN, B, 0, stream>>>(cnt, dinv);
    k_scan<<<1, 1024, 0, stream>>>(cnt, ptr);
    k_fill<<<gE, B, 0, stream>>>(row, col, ptr, csr_src);

    // ---- 3 fused conv layers ----
    k_gather<1><<<gG, B, 0, stream>>>(ptr, csr_src, dinv, x,  x,       h1,  out);
    k_gather<2><<<gG, B, 0, stream>>>(ptr, csr_src, dinv, h1, nullptr, h2,  out);
    k_gather<3><<<gG, B, 0, stream>>>(ptr, csr_src, dinv, h2, nullptr, out, out);
}

// Round 3
// 900.994 us; speedup vs baseline: 18.1670x; 1.5496x over previous
//
#include <hip/hip_runtime.h>

constexpr int N = 100000;
constexpr int D = 128;
constexpr int E = 3200000;
constexpr int NB = (N + 1023) / 1024;   // 98 scan chunks

typedef unsigned int uint;

// round-to-nearest-even float -> bf16 pair packed in a uint (lo = a, hi = b)
__device__ inline uint pack_bf16(float a, float b) {
    uint ua = __float_as_uint(a); ua += 0x7fffu + ((ua >> 16) & 1u);
    uint ub = __float_as_uint(b); ub += 0x7fffu + ((ub >> 16) & 1u);
    return (ua >> 16) | (ub & 0xffff0000u);
}
__device__ inline float lo_bf16(uint w) { return __uint_as_float(w << 16); }
__device__ inline float hi_bf16(uint w) { return __uint_as_float(w & 0xffff0000u); }

// ---------------- CSR build ----------------

__global__ void k_zero(int* __restrict__ p, int n) {
    int i = blockIdx.x * blockDim.x + threadIdx.x;
    if (i < n) p[i] = 0;
}

__global__ void k_hist(const int* __restrict__ col, int* __restrict__ cnt) {
    int e = blockIdx.x * blockDim.x + threadIdx.x;
    if (e < E) atomicAdd(&cnt[col[e]], 1);
}

// per-chunk exclusive scan + chunk totals; also dinv = rsqrt(cnt+1)
__global__ void k_scan1(const int* __restrict__ cnt, int* __restrict__ ptrE,
                        int* __restrict__ bsum, float* __restrict__ dinv) {
    __shared__ int lds[1024];
    int tid = threadIdx.x;
    int i = blockIdx.x * 1024 + tid;
    int v = (i < N) ? cnt[i] : 0;
    if (i < N) dinv[i] = rsqrtf((float)(v + 1));
    lds[tid] = v;
    __syncthreads();
    for (int ofs = 1; ofs < 1024; ofs <<= 1) {
        int t = (tid >= ofs) ? lds[tid - ofs] : 0;
        __syncthreads();
        lds[tid] += t;
        __syncthreads();
    }
    if (i < N) ptrE[i] = lds[tid] - v;
    if (tid == 1023) bsum[blockIdx.x] = lds[1023];
}

// exclusive scan of the 98 chunk totals (single tiny block)
__global__ void k_scan2(int* __restrict__ bsum) {
    __shared__ int lds[128];
    int tid = threadIdx.x;
    int v = (tid < NB) ? bsum[tid] : 0;
    lds[tid] = v;
    __syncthreads();
    for (int ofs = 1; ofs < 128; ofs <<= 1) {
        int t = (tid >= ofs) ? lds[tid - ofs] : 0;
        __syncthreads();
        lds[tid] += t;
        __syncthreads();
    }
    if (tid < NB) bsum[tid] = lds[tid] - v;
}

__global__ void k_scan3(const int* __restrict__ ptrE, const int* __restrict__ bsum,
                        int* __restrict__ ptr) {
    int i = blockIdx.x * blockDim.x + threadIdx.x;
    if (i < N) ptr[i] = ptrE[i] + bsum[i >> 10];
}

// fill CSR; ptr is the (exclusive) cursor -> afterwards ptr[c] == inclusive end
__global__ void k_fill(const int* __restrict__ row, const int* __restrict__ col,
                       int* __restrict__ ptr, int* __restrict__ csr_src) {
    int e = blockIdx.x * blockDim.x + threadIdx.x;
    if (e < E) {
        int slot = atomicAdd(&ptr[col[e]], 1);
        csr_src[slot] = row[e];
    }
}

// g0[i] = dinv[node] * x[i], packed bf16 (2 elems per uint)
__global__ void k_cvt(const float* __restrict__ x, const float* __restrict__ dinv,
                      uint* __restrict__ g0) {
    int i = blockIdx.x * blockDim.x + threadIdx.x;
    if (i >= N * (D / 2)) return;
    float s = dinv[i >> 6];
    float2 v = reinterpret_cast<const float2*>(x)[i];
    g0[i] = pack_bf16(s * v.x, s * v.y);
}

// ---------------- fused gather conv ----------------
// g[i] = dinv[i]*h[i] stored bf16.  S = g_c + sum_{e: col==c} g_src
// r (this layer's h) = dc*S ; next layer's g = dc^2*S
// FINAL=0: acc_out = aux + r ; g_out = pack(dc^2*S)
// FINAL=1: acc = (acc + r) * 0.25
template <int FINAL>
__global__ void k_gather(const int* __restrict__ ptr, const int* __restrict__ csr_src,
                         const float* __restrict__ dinv,
                         const uint* __restrict__ gb_in,
                         const float* __restrict__ aux,
                         uint* __restrict__ gb_out,
                         float* __restrict__ acc) {
    int node = blockIdx.x * (blockDim.x >> 6) + (threadIdx.x >> 6);
    if (node >= N) return;
    node = __builtin_amdgcn_readfirstlane(node);
    int lane = threadIdx.x & 63;

    int beg = (node == 0) ? 0 : ptr[node - 1];
    int end = ptr[node];
    float dc = dinv[node];

    uint w = gb_in[(size_t)node * 64 + lane];
    float Sx = lo_bf16(w), Sy = hi_bf16(w);

    int t = beg;
    for (; t + 1 < end; t += 2) {
        int s0 = csr_src[t];
        int s1 = csr_src[t + 1];
        uint u0 = gb_in[(size_t)s0 * 64 + lane];
        uint u1 = gb_in[(size_t)s1 * 64 + lane];
        Sx += lo_bf16(u0); Sy += hi_bf16(u0);
        Sx += lo_bf16(u1); Sy += hi_bf16(u1);
    }
    if (t < end) {
        uint u = gb_in[(size_t)csr_src[t] * 64 + lane];
        Sx += lo_bf16(u); Sy += hi_bf16(u);
    }

    float rx = dc * Sx, ry = dc * Sy;
    size_t o2 = (size_t)node * 64 + lane;
    if (FINAL == 0) {
        float2 av = reinterpret_cast<const float2*>(aux)[o2];
        reinterpret_cast<float2*>(acc)[o2] = make_float2(av.x + rx, av.y + ry);
        gb_out[o2] = pack_bf16(dc * rx, dc * ry);
    } else {
        float2 av = reinterpret_cast<const float2*>(acc)[o2];
        reinterpret_cast<float2*>(acc)[o2] =
            make_float2((av.x + rx) * 0.25f, (av.y + ry) * 0.25f);
    }
}

extern "C" void kernel_launch(void* const* d_in, const int* in_sizes, int n_in,
                              void* d_out, int out_size, void* d_ws, size_t ws_size,
                              hipStream_t stream) {
    const float* x  = (const float*)d_in[0];
    const int*   ei = (const int*)d_in[1];   // [2, E]: row = ei[0:E], col = ei[E:2E]
    const int*   row = ei;
    const int*   col = ei + E;
    float* out = (float*)d_out;

    // ws layout
    char* ws = (char*)d_ws;
    int*   cnt     = (int*)ws;                       // N
    int*   ptrE    = cnt + N;                        // N
    int*   ptr     = ptrE + N;                       // N
    int*   bsum    = ptr + N;                        // 128
    float* dinv    = (float*)(bsum + 128);           // N
    int*   csr_src = (int*)(dinv + N);               // E
    uint*  g0      = (uint*)(csr_src + E);           // N*64
    uint*  g1      = g0 + (size_t)N * 64;            // N*64
    uint*  g2      = g1 + (size_t)N * 64;            // N*64

    const int B = 256;
    const int gN  = (N + B - 1) / B;
    const int gE  = (E + B - 1) / B;
    const int gC  = (N * (D / 2) + B - 1) / B;
    const int gG  = (N + 3) / 4;                     // 4 waves/block, 1 node/wave

    // ---- CSR build + normalization ----
    k_zero<<<gN, B, 0, stream>>>(cnt, N);
    k_hist<<<gE, B, 0, stream>>>(col, cnt);
    k_scan1<<<NB, 1024, 0, stream>>>(cnt, ptrE, bsum, dinv);
    k_scan2<<<1, 128, 0, stream>>>(bsum);
    k_scan3<<<gN, B, 0, stream>>>(ptrE, bsum, ptr);
    k_fill<<<gE, B, 0, stream>>>(row, col, ptr, csr_src);
    k_cvt<<<gC, B, 0, stream>>>(x, dinv, g0);

    // ---- 3 fused conv layers ----
    k_gather<0><<<gG, B, 0, stream>>>(ptr, csr_src, dinv, g0, x,   g1, out);
    k_gather<0><<<gG, B, 0, stream>>>(ptr, csr_src, dinv, g1, out, g2, out);
    k_gather<1><<<gG, B, 0, stream>>>(ptr, csr_src, dinv, g2, out, nullptr, out);
}